// Round 16
// baseline (1106.263 us; speedup 1.0000x reference)
//
#include <hip/hip_runtime.h>
#include <hip/hip_bf16.h>
#include <stdint.h>

typedef __attribute__((ext_vector_type(8))) short bf16x8;
typedef __attribute__((ext_vector_type(4))) float f32x4;
typedef __attribute__((ext_vector_type(4))) unsigned short us4;

#define T_TOK 8192
#define DDIM 1024
#define FDIM 4096
#define F2DIM 2048
#define NEXP 8
#define NTPB1 4352     // prep1 transpose blocks: 4096(w1) + 256(sw1)
#define NRBLK 2048     // router blocks (4 tokens each)
#define FC1_T 5344     // fc1 GEMM block budget; ids >= FC1_T do w2/sw2 transpose

__device__ __forceinline__ unsigned short f2bf(float f) {
    unsigned u = __float_as_uint(f);
    u += 0x7fffu + ((u >> 16) & 1u);
    return (unsigned short)(u >> 16);
}
__device__ __forceinline__ float bf2f(unsigned short h) {
    return __uint_as_float(((unsigned)h) << 16);
}
__device__ __forceinline__ float gelu_fast(float v) {
    float u = 0.7978845608028654f * v * (1.0f + 0.044715f * v * v);
    float a = fabsf(u);
    float t = __expf(-2.0f * a);
    float th = (1.0f - t) / (1.0f + t);
    th = u < 0.0f ? -th : th;
    return 0.5f * v * (1.0f + th);
}

// async global->LDS, 16B per lane. LDS dest is wave-uniform base + lane*16.
__device__ __forceinline__ void gl2lds16(const void* g, void* l) {
    __builtin_amdgcn_global_load_lds(
        (const __attribute__((address_space(1))) unsigned int*)(unsigned long long)g,
        (__attribute__((address_space(3))) unsigned int*)(unsigned int)(unsigned long long)l,
        16, 0, 0);
}

// ---- one 128n x 64k transpose region -> 2 tiled 8KB units (R12-proven) ------
// ts is [64][128] (32KB): conflict count identical to the old [64][132] pad
// (both 4-way on col-reads and writes -- measured 3.3M in fc1 either way),
// but 32KB exactly enables 5 blocks/CU.
__device__ __forceinline__ void tp_block(const float* __restrict__ in,
                                         unsigned short* __restrict__ out,
                                         int Cin, long long ibase, int n0, int k0,
                                         long long unit0, float (*ts)[128], int tid) {
#pragma unroll
    for (int i = 0; i < 8; ++i) {
        int idx = tid + i * 256;
        int k = idx >> 5, t4 = idx & 31;
        float4 v = *(const float4*)(in + ibase + (long long)(k0 + k) * Cin + n0 + t4 * 4);
        *(float4*)&ts[k][t4 * 4] = v;
    }
    __syncthreads();
#pragma unroll
    for (int i = 0; i < 4; ++i) {
        int idx = tid + i * 256;           // 0..1023
        int u = idx >> 9, cid = idx & 511;
        int row = cid >> 2, c = cid & 3;
        int gc = c ^ ((row >> 1) & 3);
        const int kb = u * 32 + gc * 8;
        us4 o0, o1;
        o0.x = f2bf(ts[kb + 0][row]); o0.y = f2bf(ts[kb + 1][row]);
        o0.z = f2bf(ts[kb + 2][row]); o0.w = f2bf(ts[kb + 3][row]);
        o1.x = f2bf(ts[kb + 4][row]); o1.y = f2bf(ts[kb + 5][row]);
        o1.z = f2bf(ts[kb + 6][row]); o1.w = f2bf(ts[kb + 7][row]);
        unsigned short* dst = out + (unit0 + u) * 4096 + (long long)cid * 8;
        *(us4*)dst = o0;
        *(us4*)(dst + 4) = o1;
    }
}

// ===== prep1: w1/sw1 transpose (blocks < NTPB1) ∥ router (rest) ==============
// Router: NO global atomics -- per-block LDS histogram -> bcnt[blk][8].
__launch_bounds__(256, 5)
__global__ void k_prep1(const float* __restrict__ w1, const float* __restrict__ sw1,
                        unsigned short* __restrict__ w1t, unsigned short* __restrict__ sw1t,
                        const float* __restrict__ x, const float* __restrict__ rw,
                        const float* __restrict__ rbv, int* __restrict__ eid,
                        float* __restrict__ ewt, int* __restrict__ bcnt,
                        unsigned short* __restrict__ xb) {
    const int blk = blockIdx.x;
    const int tid = threadIdx.x;

    if (blk < NTPB1) {
        __shared__ float ts[64][128];
        if (blk < 4096) {              // w1: 8 x [K=1024][N=4096]; NB=32, slabs=16
            int e = blk >> 9, l = blk & 511;
            int nb = l >> 4, ks = l & 15;
            tp_block(w1, w1t, 4096, (long long)e * 1024 * 4096,
                     nb * 128, ks * 64, (long long)e * 1024 + nb * 32 + ks * 2, ts, tid);
        } else {                       // sw1: [K=1024][N=2048]; NB=16, slabs=16
            int l = blk - 4096;
            int nb = l >> 4, ks = l & 15;
            tp_block(sw1, sw1t, 2048, 0, nb * 128, ks * 64, nb * 32 + ks * 2, ts, tid);
        }
        return;
    }

    // ---------------- router part (zero global atomics) ----------------
    __shared__ int hcnt[8];
    const int rblk = blk - NTPB1;
    const int wid = tid >> 6, lane = tid & 63;
    const int t = rblk * 4 + wid;
    if (tid < 8) hcnt[tid] = 0;
    __syncthreads();

    float acc[8];
#pragma unroll
    for (int e = 0; e < 8; ++e) acc[e] = 0.f;
    const float4* xr = (const float4*)(x + (long long)t * DDIM);
#pragma unroll
    for (int c = 0; c < 4; ++c) {
        float4 xv = xr[lane + 64 * c];
        int d0 = (lane + 64 * c) * 4;
        us4 o;
        o.x = f2bf(xv.x); o.y = f2bf(xv.y); o.z = f2bf(xv.z); o.w = f2bf(xv.w);
        *(us4*)(xb + (long long)t * DDIM + d0) = o;
        float xs[4] = {xv.x, xv.y, xv.z, xv.w};
#pragma unroll
        for (int j = 0; j < 4; ++j) {
            const float* wrow = rw + (long long)(d0 + j) * 8;
#pragma unroll
            for (int e = 0; e < 8; ++e) acc[e] += xs[j] * wrow[e];
        }
    }
#pragma unroll
    for (int off = 32; off; off >>= 1)
#pragma unroll
        for (int e = 0; e < 8; ++e) acc[e] += __shfl_xor(acc[e], off);
    if (lane == 0) {
        float lg[8];
#pragma unroll
        for (int e = 0; e < 8; ++e) lg[e] = acc[e] + rbv[e];
        int e0 = 0;
#pragma unroll
        for (int e = 1; e < 8; ++e) if (lg[e] > lg[e0]) e0 = e;
        int e1 = -1;
#pragma unroll
        for (int e = 0; e < 8; ++e) {
            if (e == e0) continue;
            if (e1 < 0 || lg[e] > lg[e1]) e1 = e;
        }
        float w0 = 1.f / (1.f + expf(lg[e1] - lg[e0]));
        eid[2 * t] = e0; eid[2 * t + 1] = e1;
        ewt[2 * t] = w0; ewt[2 * t + 1] = 1.f - w0;
        atomicAdd(&hcnt[e0], 1);   // LDS atomic (fast)
        atomicAdd(&hcnt[e1], 1);
    }
    __syncthreads();
    if (tid < 8) bcnt[rblk * 8 + tid] = hcnt[tid];
}

// ===== route: merged scan + scatter, 32 blocks, zero atomics =================
__global__ void k_route(const int* __restrict__ bcnt, const int* __restrict__ eid,
                        const float* __restrict__ ewt, int* __restrict__ cnt,
                        int* __restrict__ offs, int* __restrict__ rowtok,
                        float* __restrict__ roww, int* __restrict__ pos) {
    __shared__ int part[8][33];
    __shared__ int ctot[8];
    __shared__ int gbase[8];
    __shared__ int lb[64][8];
    const int tid = threadIdx.x;
    const int e = tid >> 5, j = tid & 31;
    int s = 0;
    for (int r = j * 64; r < j * 64 + 64; ++r) s += bcnt[r * 8 + e];
    part[e][j] = s;
    __syncthreads();
    if (j == 0) {                      // exclusive prefix over 32 partials
        int run = 0;
        for (int k = 0; k < 32; ++k) { int v = part[e][k]; part[e][k] = run; run += v; }
        ctot[e] = run;
    }
    __syncthreads();
    if (tid == 0) {
        int run = 0;
        for (int ee = 0; ee < NEXP; ++ee) { gbase[ee] = run; run += ctot[ee]; }
        if (blockIdx.x == 0) {
            int r2 = 0;
            for (int ee = 0; ee < NEXP; ++ee) { offs[ee] = r2; cnt[ee] = ctot[ee]; r2 += ctot[ee]; }
            offs[NEXP] = r2;
        }
    }
    __syncthreads();
    if (tid < 8) {                     // bases for this block's 64 router rows
        int ee = tid;
        int run = gbase[ee] + part[ee][blockIdx.x];
        int r0 = blockIdx.x * 64;
        for (int r = 0; r < 64; ++r) {
            lb[r][ee] = run;
            run += bcnt[(r0 + r) * 8 + ee];
        }
    }
    __syncthreads();
    // scatter this block's 256 tokens
    const int t = blockIdx.x * 256 + tid;
    const int rloc = tid >> 2;
    const int g = t & 3;
    const int lane = tid & 63, lbn = lane & ~3;
    int e0 = eid[2 * t], e1 = eid[2 * t + 1];
    int r0 = 0, r1 = 0;
#pragma unroll
    for (int q = 0; q < 4; ++q) {
        int oe0 = __shfl(e0, lbn + q, 64);
        int oe1 = __shfl(e1, lbn + q, 64);
        if (q < g) {
            r0 += (oe0 == e0) + (oe1 == e0);
            r1 += (oe0 == e1) + (oe1 == e1);
        }
    }
    int p0 = lb[rloc][e0] + r0;
    int p1 = lb[rloc][e1] + r1;
    rowtok[p0] = (t << 1);     roww[p0] = ewt[2 * t];     pos[2 * t] = p0;
    rowtok[p1] = (t << 1) | 1; roww[p1] = ewt[2 * t + 1]; pos[2 * t + 1] = p1;
}

// ---- grouped GEMM (R15 core) + (FC==1) fused w2/sw2 transpose ---------------
// LDS exactly 32KB -> 5 blocks/CU (160KB). fc1 tile order (cbg, rb, cbi)
// panel-groups of 4 (A x4 back-to-back, B-group L2-resident, A swept 8x);
// fc2 cb-fastest. XCD bijective swizzle. 0-conflict GEMM LDS swizzle.
template <int FC>
__launch_bounds__(256, 5)
__global__ void k_fc(const short* __restrict__ Amoe, const short* __restrict__ Ash,
                     const short* __restrict__ Bmoe, const short* __restrict__ Bsh,
                     const float* __restrict__ biasM, const float* __restrict__ biasS,
                     const float* __restrict__ gateM, const float* __restrict__ gateS,
                     unsigned short* __restrict__ outM, unsigned short* __restrict__ outS,
                     const int* __restrict__ cnt, const int* __restrict__ offs,
                     const int* __restrict__ rowtok, const float* __restrict__ roww,
                     const float* __restrict__ swp,
                     const float* __restrict__ w2raw, const float* __restrict__ sw2raw,
                     unsigned short* __restrict__ w2t_o, unsigned short* __restrict__ sw2t_o) {
    __shared__ __align__(16) char smem_raw[32768];

    if (FC == 1 && blockIdx.x >= FC1_T) {
        float (*ts)[128] = (float(*)[128])smem_raw;
        int tb = blockIdx.x - FC1_T;
        if (tb < 4096) {               // w2: 8 x [K=4096][N=1024]; NB=8, slabs=64
            int e = tb >> 9, l = tb & 511;
            int nb = l >> 6, ks = l & 63;
            tp_block(w2raw, w2t_o, 1024, (long long)e * 4096 * 1024,
                     nb * 128, ks * 64, (long long)e * 1024 + nb * 128 + ks * 2,
                     ts, threadIdx.x);
        } else {                       // sw2: [K=2048][N=1024]; NB=8, slabs=32
            int l = tb - 4096;
            int nb = l >> 5, ks = l & 31;
            tp_block(sw2raw, sw2t_o, 1024, 0, nb * 128, ks * 64,
                     nb * 64 + ks * 2, ts, threadIdx.x);
        }
        return;
    }

    // ---- tile decode ----
    int RBz[9];
    int T = 0;
#pragma unroll
    for (int zz = 0; zz < 9; ++zz) {
        int Mz = (zz < 8) ? cnt[zz] : T_TOK;
        int rbn = (Mz + 127) >> 7;
        int cbn = (FC == 1) ? ((zz < 8) ? 32 : 16) : 8;
        RBz[zz] = rbn;
        T += rbn * cbn;
    }
    const int ell = blockIdx.x;
    if (ell >= T) return;
    const int q = T >> 3, r = T & 7;
    const int xk = ell & 7, jj = ell >> 3;
    int t = (xk < r ? xk * (q + 1) : r * (q + 1) + (xk - r) * q) + jj;

    int z = 0, local = t;
    for (; z < 9; ++z) {
        int cbn = (FC == 1) ? ((z < 8) ? 32 : 16) : 8;
        int tz = RBz[z] * cbn;
        if (local < tz) break;
        local -= tz;
    }
    const int RB = RBz[z];
    int cb, rb;
    if (FC == 1) {                 // panel groups of 4: (cbg, rb, cbi)
        int grp = RB * 4;
        int cbg = local / grp;
        int r2 = local - cbg * grp;
        rb = r2 >> 2;
        cb = cbg * 4 + (r2 & 3);
    } else {                       // cb fastest: A-tile reuse (CBN = 8)
        rb = local >> 3;
        cb = local & 7;
    }

    const bool sh = (z == 8);
    const int Kd = (FC == 1) ? 1024 : (sh ? 2048 : 4096);
    const int Ncols = (FC == 1) ? (sh ? 2048 : 4096) : 1024;
    const int KB = Kd / 32;        // units per B column-panel
    const int M = sh ? T_TOK : cnt[z];
    const int oE = sh ? 0 : offs[z];

    const short* A = sh ? Ash : Amoe;
    const short* B = sh ? Bsh : Bmoe + (long long)z * 4194304;

    short* Asb = (short*)smem_raw;        // [2][4096]
    short* Bsb = Asb + 8192;              // [2][4096]

    const int tid = threadIdx.x, w = tid >> 6, lane = tid & 63;
    const int fr = lane & 15, fg = lane >> 4;
    const int wr = w >> 1, wc = w & 1;

    const short *ag0, *ag1;
    {
        int id = tid, row = id >> 2;
        int gc = (id & 3) ^ ((row >> 1) & 3);
        int rA = rb * 128 + row; if (rA > M - 1) rA = M - 1;
        long long rowix;
        if (FC == 1) rowix = sh ? (long long)rA : (long long)(rowtok[oE + rA] >> 1);
        else         rowix = sh ? (long long)rA : (long long)(oE + rA);
        ag0 = A + rowix * (long long)Kd + gc * 8;
    }
    {
        int id = tid + 256, row = id >> 2;
        int gc = (id & 3) ^ ((row >> 1) & 3);
        int rA = rb * 128 + row; if (rA > M - 1) rA = M - 1;
        long long rowix;
        if (FC == 1) rowix = sh ? (long long)rA : (long long)(rowtok[oE + rA] >> 1);
        else         rowix = sh ? (long long)rA : (long long)(oE + rA);
        ag1 = A + rowix * (long long)Kd + gc * 8;
    }
    const short* bb = B + (long long)cb * KB * 4096 + (long long)tid * 8;

    short* const a0d0 = Asb + w * 512;
    short* const a0d1 = Asb + 2048 + w * 512;
    short* const a1d0 = Asb + 4096 + w * 512;
    short* const a1d1 = Asb + 4096 + 2048 + w * 512;
    short* const b0d0 = Bsb + w * 512;
    short* const b0d1 = Bsb + 2048 + w * 512;
    short* const b1d0 = Bsb + 4096 + w * 512;
    short* const b1d1 = Bsb + 4096 + 2048 + w * 512;

    f32x4 acc[4][4];
#pragma unroll
    for (int m = 0; m < 4; ++m)
#pragma unroll
        for (int n = 0; n < 4; ++n)
            acc[m][n] = (f32x4){0.f, 0.f, 0.f, 0.f};

    const int slot = fg ^ ((fr >> 1) & 3);     // measured 0-conflict formula
    const int arow0 = wr * 64 + fr;
    const int brow0 = wc * 64 + fr;
    const int nk = Kd / 64;

    for (int kt = 0; kt < nk; ++kt) {
        gl2lds16(ag0, a0d0);       gl2lds16(ag0 + 32, a1d0);
        gl2lds16(ag1, a0d1);       gl2lds16(ag1 + 32, a1d1);
        gl2lds16(bb, b0d0);        gl2lds16(bb + 2048, b0d1);
        gl2lds16(bb + 4096, b1d0); gl2lds16(bb + 6144, b1d1);
        ag0 += 64; ag1 += 64; bb += 8192;
        __syncthreads();

#pragma unroll
        for (int s = 0; s < 2; ++s) {
            bf16x8 a[4], b[4];
#pragma unroll
            for (int m = 0; m < 4; ++m)
                a[m] = *(const bf16x8*)(Asb + s * 4096 + (arow0 + m * 16) * 32 + slot * 8);
#pragma unroll
            for (int n = 0; n < 4; ++n)
                b[n] = *(const bf16x8*)(Bsb + s * 4096 + (brow0 + n * 16) * 32 + slot * 8);
#pragma unroll
            for (int m = 0; m < 4; ++m)
#pragma unroll
                for (int n = 0; n < 4; ++n)
                    acc[m][n] = __builtin_amdgcn_mfma_f32_16x16x32_bf16(a[m], b[n], acc[m][n], 0, 0, 0);
        }
        __syncthreads();
    }

    // ---- epilogue. C/D layout: col=lane&15, row=(lane>>4)*4+i. n-innermost. ----
    const int mrow0 = rb * 128 + wr * 64;
    const int col0 = cb * 128 + wc * 64;

    if (FC == 1) {
        const float* bp = sh ? biasS : biasM + (long long)z * FDIM;
        const float* gp = sh ? gateS : gateM + (long long)z * FDIM;
        unsigned short* outp = sh ? outS : outM;
        const long long obase = sh ? 0 : (long long)oE;
        float bv[4], gv[4]; int coln[4];
#pragma unroll
        for (int n = 0; n < 4; ++n) {
            coln[n] = col0 + n * 16 + fr;
            bv[n] = bp[coln[n]];
            gv[n] = gp[coln[n]];
        }
#pragma unroll
        for (int m = 0; m < 4; ++m) {
#pragma unroll
            for (int i = 0; i < 4; ++i) {
                int grow = mrow0 + m * 16 + fg * 4 + i;
                if (grow < M) {
                    unsigned short* rowp = outp + (obase + grow) * (long long)Ncols;
#pragma unroll
                    for (int n = 0; n < 4; ++n) {
                        float v = (acc[m][n][i] + bv[n]) * gv[n];
                        rowp[coln[n]] = f2bf(gelu_fast(v));
                    }
                }
            }
        }
    } else {
        float bv[4]; int coln[4];
        const float* bp = sh ? biasS : biasM + (long long)z * DDIM;
#pragma unroll
        for (int n = 0; n < 4; ++n) {
            coln[n] = col0 + n * 16 + fr;
            bv[n] = bp[coln[n]];
        }
        if (sh) {
            float sigw = 1.f / (1.f + expf(-swp[0]));
#pragma unroll
            for (int m = 0; m < 4; ++m) {
#pragma unroll
                for (int i = 0; i < 4; ++i) {
                    int grow = mrow0 + m * 16 + fg * 4 + i;
                    if (grow < M) {
                        unsigned short* rowp = outS + (long long)grow * DDIM;
#pragma unroll
                        for (int n = 0; n < 4; ++n)
                            rowp[coln[n]] = f2bf((acc[m][n][i] + bv[n]) * sigw);
                    }
                }
            }
        } else {
#pragma unroll
            for (int m = 0; m < 4; ++m) {
#pragma unroll
                for (int i = 0; i < 4; ++i) {
                    int grow = mrow0 + m * 16 + fg * 4 + i;
                    if (grow < M) {
                        int p = oE + grow;
                        float wv = roww[p];
                        unsigned short* rowp = outM + (long long)p * DDIM;   // compact
#pragma unroll
                        for (int n = 0; n < 4; ++n)
                            rowp[coln[n]] = f2bf((acc[m][n][i] + bv[n]) * wv);
                    }
                }
            }
        }
    }
}

// ------- final: y = ycomp[pos0]+ycomp[pos1]+ysh ; LayerNorm over D -------
__global__ void k_ln(const unsigned short* __restrict__ yc,
                     const unsigned short* __restrict__ ysh,
                     const int* __restrict__ pos,
                     const float* __restrict__ g, const float* __restrict__ b,
                     float* __restrict__ out) {
    const int wid = threadIdx.x >> 6, lane = threadIdx.x & 63;
    const long long t = (long long)blockIdx.x * 4 + wid;
    const long long b0 = (long long)pos[2 * t] * DDIM;
    const long long b1 = (long long)pos[2 * t + 1] * DDIM;
    const long long bs = t * DDIM;
    float v[16];
    float s = 0.f, sq = 0.f;
#pragma unroll
    for (int j = 0; j < 2; ++j) {
        int c0 = (lane + 64 * j) * 8;
        uint4 a0 = *(const uint4*)(yc + b0 + c0);
        uint4 a1 = *(const uint4*)(yc + b1 + c0);
        uint4 a2 = *(const uint4*)(ysh + bs + c0);
        const unsigned* u0 = (const unsigned*)&a0;
        const unsigned* u1 = (const unsigned*)&a1;
        const unsigned* u2 = (const unsigned*)&a2;
#pragma unroll
        for (int qq = 0; qq < 4; ++qq) {
            float lo = bf2f((unsigned short)u0[qq]) + bf2f((unsigned short)u1[qq]) +
                       bf2f((unsigned short)u2[qq]);
            float hi = bf2f((unsigned short)(u0[qq] >> 16)) + bf2f((unsigned short)(u1[qq] >> 16)) +
                       bf2f((unsigned short)(u2[qq] >> 16));
            v[j * 8 + qq * 2] = lo;
            v[j * 8 + qq * 2 + 1] = hi;
            s += lo + hi;
            sq += lo * lo + hi * hi;
        }
    }
#pragma unroll
    for (int off = 32; off; off >>= 1) {
        s += __shfl_xor(s, off);
        sq += __shfl_xor(sq, off);
    }
    const float mean = s * (1.f / DDIM);
    const float var = sq * (1.f / DDIM) - mean * mean;
    const float inv = rsqrtf(var + 1e-5f);
#pragma unroll
    for (int j = 0; j < 2; ++j) {
        int c0 = (lane + 64 * j) * 8;
#pragma unroll
        for (int h = 0; h < 2; ++h) {
            float4 o4;
            float* op = (float*)&o4;
#pragma unroll
            for (int qq = 0; qq < 4; ++qq) {
                int k = h * 4 + qq;
                int col = c0 + k;
                op[qq] = (v[j * 8 + k] - mean) * inv * g[col] + b[col];
            }
            *(float4*)(out + bs + c0 + h * 4) = o4;
        }
    }
}

extern "C" void kernel_launch(void* const* d_in, const int* in_sizes, int n_in,
                              void* d_out, int out_size, void* d_ws, size_t ws_size,
                              hipStream_t stream) {
    const float* x    = (const float*)d_in[0];
    const float* rw   = (const float*)d_in[1];
    const float* rb   = (const float*)d_in[2];
    const float* w1   = (const float*)d_in[3];
    const float* b1   = (const float*)d_in[4];
    const float* gate = (const float*)d_in[5];
    const float* w2   = (const float*)d_in[6];
    const float* b2   = (const float*)d_in[7];
    const float* sw1  = (const float*)d_in[8];
    const float* sb1  = (const float*)d_in[9];
    const float* sgate= (const float*)d_in[10];
    const float* sw2  = (const float*)d_in[11];
    const float* sb2  = (const float*)d_in[12];
    const float* swt  = (const float*)d_in[13];
    const float* lng  = (const float*)d_in[14];
    const float* lnb  = (const float*)d_in[15];
    float* out = (float*)d_out;

    char* p = (char*)d_ws;
    auto take = [&](size_t n) { char* r = p; p += (n + 255) & ~(size_t)255; return r; };
    short* xb   = (short*)take((size_t)T_TOK * DDIM * 2);
    short* w1t  = (short*)take((size_t)NEXP * FDIM * DDIM * 2);
    short* w2t  = (short*)take((size_t)NEXP * DDIM * FDIM * 2);
    short* sw1t = (short*)take((size_t)F2DIM * DDIM * 2);
    short* sw2t = (short*)take((size_t)DDIM * F2DIM * 2);
    short* hbuf = (short*)take((size_t)2 * T_TOK * FDIM * 2);
    short* hs   = (short*)take((size_t)T_TOK * F2DIM * 2);
    unsigned short* ycomp = (unsigned short*)take((size_t)2 * T_TOK * DDIM * 2);
    unsigned short* ysh   = (unsigned short*)take((size_t)T_TOK * DDIM * 2);
    int* eid    = (int*)take((size_t)T_TOK * 2 * 4);
    float* ewt  = (float*)take((size_t)T_TOK * 2 * 4);
    int* rowtok = (int*)take((size_t)2 * T_TOK * 4);
    float* roww = (float*)take((size_t)2 * T_TOK * 4);
    int* pos    = (int*)take((size_t)2 * T_TOK * 4);
    int* bcnt   = (int*)take((size_t)NRBLK * 8 * 4);
    int* cnt    = (int*)take(64);
    int* offs   = (int*)take(64);

    // prep1: w1/sw1 tiled transpose (4352 blocks) + router (2048 blocks)
    k_prep1<<<NTPB1 + NRBLK, 256, 0, stream>>>(
        w1, sw1, (unsigned short*)w1t, (unsigned short*)sw1t,
        x, rw, rb, eid, ewt, bcnt, (unsigned short*)xb);

    // merged scan + scatter (deterministic, zero atomics)
    k_route<<<32, 256, 0, stream>>>(bcnt, eid, ewt, cnt, offs, rowtok, roww, pos);

    // fc1: FC1_T GEMM blocks + 4096 (w2) + 256 (sw2) fused transpose blocks
    k_fc<1><<<FC1_T + 4096 + 256, 256, 0, stream>>>(
        xb, xb, w1t, sw1t, b1, sb1, gate, sgate,
        (unsigned short*)hbuf, (unsigned short*)hs, cnt, offs, rowtok, roww, swt,
        w2, sw2, (unsigned short*)w2t, (unsigned short*)sw2t);
    // fc2: tiles = sum_e ceil(cnt/128)*8 (<= 1080) + shared 64*8=512
    k_fc<2><<<1592, 256, 0, stream>>>(
        hbuf, hs, w2t, sw2t, b2, sb2, (const float*)nullptr, (const float*)nullptr,
        ycomp, ysh, cnt, offs, rowtok, roww, swt,
        (const float*)nullptr, (const float*)nullptr,
        (unsigned short*)nullptr, (unsigned short*)nullptr);

    k_ln<<<T_TOK / 4, 256, 0, stream>>>(ycomp, ysh, pos, lng, lnb, out);
}

// Round 17
// 572.145 us; speedup vs baseline: 1.9335x; 1.9335x over previous
//
#include <hip/hip_runtime.h>
#include <hip/hip_bf16.h>
#include <stdint.h>

typedef __attribute__((ext_vector_type(8))) short bf16x8;
typedef __attribute__((ext_vector_type(4))) float f32x4;
typedef __attribute__((ext_vector_type(4))) unsigned short us4;

#define T_TOK 8192
#define DDIM 1024
#define FDIM 4096
#define F2DIM 2048
#define NEXP 8
#define NTPB1 4352     // prep1 transpose blocks: 4096(w1) + 256(sw1)
#define NRBLK 2048     // router blocks (4 tokens each)
#define FC1_T 5344     // fc1 GEMM block budget; ids >= FC1_T do w2/sw2 transpose

__device__ __forceinline__ unsigned short f2bf(float f) {
    unsigned u = __float_as_uint(f);
    u += 0x7fffu + ((u >> 16) & 1u);
    return (unsigned short)(u >> 16);
}
__device__ __forceinline__ float bf2f(unsigned short h) {
    return __uint_as_float(((unsigned)h) << 16);
}
__device__ __forceinline__ float gelu_fast(float v) {
    float u = 0.7978845608028654f * v * (1.0f + 0.044715f * v * v);
    float a = fabsf(u);
    float t = __expf(-2.0f * a);
    float th = (1.0f - t) / (1.0f + t);
    th = u < 0.0f ? -th : th;
    return 0.5f * v * (1.0f + th);
}

// async global->LDS, 16B per lane. LDS dest is wave-uniform base + lane*16.
__device__ __forceinline__ void gl2lds16(const void* g, void* l) {
    __builtin_amdgcn_global_load_lds(
        (const __attribute__((address_space(1))) unsigned int*)(unsigned long long)g,
        (__attribute__((address_space(3))) unsigned int*)(unsigned int)(unsigned long long)l,
        16, 0, 0);
}

// ---- one 128n x 64k transpose region -> 2 tiled 8KB units (R12-proven) ------
// ts is [64][128] (32KB): same conflict count as padded variant, fits 32KB.
__device__ __forceinline__ void tp_block(const float* __restrict__ in,
                                         unsigned short* __restrict__ out,
                                         int Cin, long long ibase, int n0, int k0,
                                         long long unit0, float (*ts)[128], int tid) {
#pragma unroll
    for (int i = 0; i < 8; ++i) {
        int idx = tid + i * 256;
        int k = idx >> 5, t4 = idx & 31;
        float4 v = *(const float4*)(in + ibase + (long long)(k0 + k) * Cin + n0 + t4 * 4);
        *(float4*)&ts[k][t4 * 4] = v;
    }
    __syncthreads();
#pragma unroll
    for (int i = 0; i < 4; ++i) {
        int idx = tid + i * 256;           // 0..1023
        int u = idx >> 9, cid = idx & 511;
        int row = cid >> 2, c = cid & 3;
        int gc = c ^ ((row >> 1) & 3);
        const int kb = u * 32 + gc * 8;
        us4 o0, o1;
        o0.x = f2bf(ts[kb + 0][row]); o0.y = f2bf(ts[kb + 1][row]);
        o0.z = f2bf(ts[kb + 2][row]); o0.w = f2bf(ts[kb + 3][row]);
        o1.x = f2bf(ts[kb + 4][row]); o1.y = f2bf(ts[kb + 5][row]);
        o1.z = f2bf(ts[kb + 6][row]); o1.w = f2bf(ts[kb + 7][row]);
        unsigned short* dst = out + (unit0 + u) * 4096 + (long long)cid * 8;
        *(us4*)dst = o0;
        *(us4*)(dst + 4) = o1;
    }
}

// ===== prep1: w1/sw1 transpose (blocks < NTPB1) ∥ router (rest) ==============
// Router: NO global atomics -- per-block LDS histogram -> bcnt[blk][8].
__global__ void k_prep1(const float* __restrict__ w1, const float* __restrict__ sw1,
                        unsigned short* __restrict__ w1t, unsigned short* __restrict__ sw1t,
                        const float* __restrict__ x, const float* __restrict__ rw,
                        const float* __restrict__ rbv, int* __restrict__ eid,
                        float* __restrict__ ewt, int* __restrict__ bcnt,
                        unsigned short* __restrict__ xb) {
    const int blk = blockIdx.x;
    const int tid = threadIdx.x;

    if (blk < NTPB1) {
        __shared__ float ts[64][128];
        if (blk < 4096) {              // w1: 8 x [K=1024][N=4096]; NB=32, slabs=16
            int e = blk >> 9, l = blk & 511;
            int nb = l >> 4, ks = l & 15;
            tp_block(w1, w1t, 4096, (long long)e * 1024 * 4096,
                     nb * 128, ks * 64, (long long)e * 1024 + nb * 32 + ks * 2, ts, tid);
        } else {                       // sw1: [K=1024][N=2048]; NB=16, slabs=16
            int l = blk - 4096;
            int nb = l >> 4, ks = l & 15;
            tp_block(sw1, sw1t, 2048, 0, nb * 128, ks * 64, nb * 32 + ks * 2, ts, tid);
        }
        return;
    }

    // ---------------- router part (zero global atomics) ----------------
    __shared__ int hcnt[8];
    const int rblk = blk - NTPB1;
    const int wid = tid >> 6, lane = tid & 63;
    const int t = rblk * 4 + wid;
    if (tid < 8) hcnt[tid] = 0;
    __syncthreads();

    float acc[8];
#pragma unroll
    for (int e = 0; e < 8; ++e) acc[e] = 0.f;
    const float4* xr = (const float4*)(x + (long long)t * DDIM);
#pragma unroll
    for (int c = 0; c < 4; ++c) {
        float4 xv = xr[lane + 64 * c];
        int d0 = (lane + 64 * c) * 4;
        us4 o;
        o.x = f2bf(xv.x); o.y = f2bf(xv.y); o.z = f2bf(xv.z); o.w = f2bf(xv.w);
        *(us4*)(xb + (long long)t * DDIM + d0) = o;
        float xs[4] = {xv.x, xv.y, xv.z, xv.w};
#pragma unroll
        for (int j = 0; j < 4; ++j) {
            const float* wrow = rw + (long long)(d0 + j) * 8;
#pragma unroll
            for (int e = 0; e < 8; ++e) acc[e] += xs[j] * wrow[e];
        }
    }
#pragma unroll
    for (int off = 32; off; off >>= 1)
#pragma unroll
        for (int e = 0; e < 8; ++e) acc[e] += __shfl_xor(acc[e], off);
    if (lane == 0) {
        float lg[8];
#pragma unroll
        for (int e = 0; e < 8; ++e) lg[e] = acc[e] + rbv[e];
        int e0 = 0;
#pragma unroll
        for (int e = 1; e < 8; ++e) if (lg[e] > lg[e0]) e0 = e;
        int e1 = -1;
#pragma unroll
        for (int e = 0; e < 8; ++e) {
            if (e == e0) continue;
            if (e1 < 0 || lg[e] > lg[e1]) e1 = e;
        }
        float w0 = 1.f / (1.f + expf(lg[e1] - lg[e0]));
        eid[2 * t] = e0; eid[2 * t + 1] = e1;
        ewt[2 * t] = w0; ewt[2 * t + 1] = 1.f - w0;
        atomicAdd(&hcnt[e0], 1);   // LDS atomic (fast)
        atomicAdd(&hcnt[e1], 1);
    }
    __syncthreads();
    if (tid < 8) bcnt[rblk * 8 + tid] = hcnt[tid];
}

// ===== route: merged scan + scatter, 32 blocks, zero atomics =================
__global__ void k_route(const int* __restrict__ bcnt, const int* __restrict__ eid,
                        const float* __restrict__ ewt, int* __restrict__ cnt,
                        int* __restrict__ offs, int* __restrict__ rowtok,
                        float* __restrict__ roww, int* __restrict__ pos) {
    __shared__ int part[8][33];
    __shared__ int ctot[8];
    __shared__ int gbase[8];
    __shared__ int lb[64][8];
    const int tid = threadIdx.x;
    const int e = tid >> 5, j = tid & 31;
    int s = 0;
    for (int r = j * 64; r < j * 64 + 64; ++r) s += bcnt[r * 8 + e];
    part[e][j] = s;
    __syncthreads();
    if (j == 0) {                      // exclusive prefix over 32 partials
        int run = 0;
        for (int k = 0; k < 32; ++k) { int v = part[e][k]; part[e][k] = run; run += v; }
        ctot[e] = run;
    }
    __syncthreads();
    if (tid == 0) {
        int run = 0;
        for (int ee = 0; ee < NEXP; ++ee) { gbase[ee] = run; run += ctot[ee]; }
        if (blockIdx.x == 0) {
            int r2 = 0;
            for (int ee = 0; ee < NEXP; ++ee) { offs[ee] = r2; cnt[ee] = ctot[ee]; r2 += ctot[ee]; }
            offs[NEXP] = r2;
        }
    }
    __syncthreads();
    if (tid < 8) {                     // bases for this block's 64 router rows
        int ee = tid;
        int run = gbase[ee] + part[ee][blockIdx.x];
        int r0 = blockIdx.x * 64;
        for (int r = 0; r < 64; ++r) {
            lb[r][ee] = run;
            run += bcnt[(r0 + r) * 8 + ee];
        }
    }
    __syncthreads();
    // scatter this block's 256 tokens
    const int t = blockIdx.x * 256 + tid;
    const int rloc = tid >> 2;
    const int g = t & 3;
    const int lane = tid & 63, lbn = lane & ~3;
    int e0 = eid[2 * t], e1 = eid[2 * t + 1];
    int r0 = 0, r1 = 0;
#pragma unroll
    for (int q = 0; q < 4; ++q) {
        int oe0 = __shfl(e0, lbn + q, 64);
        int oe1 = __shfl(e1, lbn + q, 64);
        if (q < g) {
            r0 += (oe0 == e0) + (oe1 == e0);
            r1 += (oe0 == e1) + (oe1 == e1);
        }
    }
    int p0 = lb[rloc][e0] + r0;
    int p1 = lb[rloc][e1] + r1;
    rowtok[p0] = (t << 1);     roww[p0] = ewt[2 * t];     pos[2 * t] = p0;
    rowtok[p1] = (t << 1) | 1; roww[p1] = ewt[2 * t + 1]; pos[2 * t + 1] = p1;
}

// ---- grouped GEMM (R15 core) + (FC==1) fused w2/sw2 transpose ---------------
// LDS exactly 32KB; __launch_bounds__(256,4) so the allocator keeps the natural
// 64 VGPRs (R16's (256,5) forced 48 -> acc spilled to scratch, 3x regression).
// HW may still opportunistically co-schedule a 5th block (LDS 160/32=5).
template <int FC>
__launch_bounds__(256, 4)
__global__ void k_fc(const short* __restrict__ Amoe, const short* __restrict__ Ash,
                     const short* __restrict__ Bmoe, const short* __restrict__ Bsh,
                     const float* __restrict__ biasM, const float* __restrict__ biasS,
                     const float* __restrict__ gateM, const float* __restrict__ gateS,
                     unsigned short* __restrict__ outM, unsigned short* __restrict__ outS,
                     const int* __restrict__ cnt, const int* __restrict__ offs,
                     const int* __restrict__ rowtok, const float* __restrict__ roww,
                     const float* __restrict__ swp,
                     const float* __restrict__ w2raw, const float* __restrict__ sw2raw,
                     unsigned short* __restrict__ w2t_o, unsigned short* __restrict__ sw2t_o) {
    __shared__ __align__(16) char smem_raw[32768];

    if (FC == 1 && blockIdx.x >= FC1_T) {
        float (*ts)[128] = (float(*)[128])smem_raw;
        int tb = blockIdx.x - FC1_T;
        if (tb < 4096) {               // w2: 8 x [K=4096][N=1024]; NB=8, slabs=64
            int e = tb >> 9, l = tb & 511;
            int nb = l >> 6, ks = l & 63;
            tp_block(w2raw, w2t_o, 1024, (long long)e * 4096 * 1024,
                     nb * 128, ks * 64, (long long)e * 1024 + nb * 128 + ks * 2,
                     ts, threadIdx.x);
        } else {                       // sw2: [K=2048][N=1024]; NB=8, slabs=32
            int l = tb - 4096;
            int nb = l >> 5, ks = l & 31;
            tp_block(sw2raw, sw2t_o, 1024, 0, nb * 128, ks * 64,
                     nb * 64 + ks * 2, ts, threadIdx.x);
        }
        return;
    }

    // ---- tile decode ----
    int RBz[9];
    int T = 0;
#pragma unroll
    for (int zz = 0; zz < 9; ++zz) {
        int Mz = (zz < 8) ? cnt[zz] : T_TOK;
        int rbn = (Mz + 127) >> 7;
        int cbn = (FC == 1) ? ((zz < 8) ? 32 : 16) : 8;
        RBz[zz] = rbn;
        T += rbn * cbn;
    }
    const int ell = blockIdx.x;
    if (ell >= T) return;
    const int q = T >> 3, r = T & 7;
    const int xk = ell & 7, jj = ell >> 3;
    int t = (xk < r ? xk * (q + 1) : r * (q + 1) + (xk - r) * q) + jj;

    int z = 0, local = t;
    for (; z < 9; ++z) {
        int cbn = (FC == 1) ? ((z < 8) ? 32 : 16) : 8;
        int tz = RBz[z] * cbn;
        if (local < tz) break;
        local -= tz;
    }
    const int RB = RBz[z];
    int cb, rb;
    if (FC == 1) {                 // panel groups of 4: (cbg, rb, cbi)
        int grp = RB * 4;
        int cbg = local / grp;
        int r2 = local - cbg * grp;
        rb = r2 >> 2;
        cb = cbg * 4 + (r2 & 3);
    } else {                       // cb fastest: A-tile reuse (CBN = 8)
        rb = local >> 3;
        cb = local & 7;
    }

    const bool sh = (z == 8);
    const int Kd = (FC == 1) ? 1024 : (sh ? 2048 : 4096);
    const int Ncols = (FC == 1) ? (sh ? 2048 : 4096) : 1024;
    const int KB = Kd / 32;        // units per B column-panel
    const int M = sh ? T_TOK : cnt[z];
    const int oE = sh ? 0 : offs[z];

    const short* A = sh ? Ash : Amoe;
    const short* B = sh ? Bsh : Bmoe + (long long)z * 4194304;

    short* Asb = (short*)smem_raw;        // [2][4096]
    short* Bsb = Asb + 8192;              // [2][4096]

    const int tid = threadIdx.x, w = tid >> 6, lane = tid & 63;
    const int fr = lane & 15, fg = lane >> 4;
    const int wr = w >> 1, wc = w & 1;

    const short *ag0, *ag1;
    {
        int id = tid, row = id >> 2;
        int gc = (id & 3) ^ ((row >> 1) & 3);
        int rA = rb * 128 + row; if (rA > M - 1) rA = M - 1;
        long long rowix;
        if (FC == 1) rowix = sh ? (long long)rA : (long long)(rowtok[oE + rA] >> 1);
        else         rowix = sh ? (long long)rA : (long long)(oE + rA);
        ag0 = A + rowix * (long long)Kd + gc * 8;
    }
    {
        int id = tid + 256, row = id >> 2;
        int gc = (id & 3) ^ ((row >> 1) & 3);
        int rA = rb * 128 + row; if (rA > M - 1) rA = M - 1;
        long long rowix;
        if (FC == 1) rowix = sh ? (long long)rA : (long long)(rowtok[oE + rA] >> 1);
        else         rowix = sh ? (long long)rA : (long long)(oE + rA);
        ag1 = A + rowix * (long long)Kd + gc * 8;
    }
    const short* bb = B + (long long)cb * KB * 4096 + (long long)tid * 8;

    short* const a0d0 = Asb + w * 512;
    short* const a0d1 = Asb + 2048 + w * 512;
    short* const a1d0 = Asb + 4096 + w * 512;
    short* const a1d1 = Asb + 4096 + 2048 + w * 512;
    short* const b0d0 = Bsb + w * 512;
    short* const b0d1 = Bsb + 2048 + w * 512;
    short* const b1d0 = Bsb + 4096 + w * 512;
    short* const b1d1 = Bsb + 4096 + 2048 + w * 512;

    f32x4 acc[4][4];
#pragma unroll
    for (int m = 0; m < 4; ++m)
#pragma unroll
        for (int n = 0; n < 4; ++n)
            acc[m][n] = (f32x4){0.f, 0.f, 0.f, 0.f};

    const int slot = fg ^ ((fr >> 1) & 3);     // measured 0-conflict formula
    const int arow0 = wr * 64 + fr;
    const int brow0 = wc * 64 + fr;
    const int nk = Kd / 64;

    for (int kt = 0; kt < nk; ++kt) {
        gl2lds16(ag0, a0d0);       gl2lds16(ag0 + 32, a1d0);
        gl2lds16(ag1, a0d1);       gl2lds16(ag1 + 32, a1d1);
        gl2lds16(bb, b0d0);        gl2lds16(bb + 2048, b0d1);
        gl2lds16(bb + 4096, b1d0); gl2lds16(bb + 6144, b1d1);
        ag0 += 64; ag1 += 64; bb += 8192;
        __syncthreads();

#pragma unroll
        for (int s = 0; s < 2; ++s) {
            bf16x8 a[4], b[4];
#pragma unroll
            for (int m = 0; m < 4; ++m)
                a[m] = *(const bf16x8*)(Asb + s * 4096 + (arow0 + m * 16) * 32 + slot * 8);
#pragma unroll
            for (int n = 0; n < 4; ++n)
                b[n] = *(const bf16x8*)(Bsb + s * 4096 + (brow0 + n * 16) * 32 + slot * 8);
#pragma unroll
            for (int m = 0; m < 4; ++m)
#pragma unroll
                for (int n = 0; n < 4; ++n)
                    acc[m][n] = __builtin_amdgcn_mfma_f32_16x16x32_bf16(a[m], b[n], acc[m][n], 0, 0, 0);
        }
        __syncthreads();
    }

    // ---- epilogue. C/D layout: col=lane&15, row=(lane>>4)*4+i. n-innermost. ----
    const int mrow0 = rb * 128 + wr * 64;
    const int col0 = cb * 128 + wc * 64;

    if (FC == 1) {
        const float* bp = sh ? biasS : biasM + (long long)z * FDIM;
        const float* gp = sh ? gateS : gateM + (long long)z * FDIM;
        unsigned short* outp = sh ? outS : outM;
        const long long obase = sh ? 0 : (long long)oE;
        float bv[4], gv[4]; int coln[4];
#pragma unroll
        for (int n = 0; n < 4; ++n) {
            coln[n] = col0 + n * 16 + fr;
            bv[n] = bp[coln[n]];
            gv[n] = gp[coln[n]];
        }
#pragma unroll
        for (int m = 0; m < 4; ++m) {
#pragma unroll
            for (int i = 0; i < 4; ++i) {
                int grow = mrow0 + m * 16 + fg * 4 + i;
                if (grow < M) {
                    unsigned short* rowp = outp + (obase + grow) * (long long)Ncols;
#pragma unroll
                    for (int n = 0; n < 4; ++n) {
                        float v = (acc[m][n][i] + bv[n]) * gv[n];
                        rowp[coln[n]] = f2bf(gelu_fast(v));
                    }
                }
            }
        }
    } else {
        float bv[4]; int coln[4];
        const float* bp = sh ? biasS : biasM + (long long)z * DDIM;
#pragma unroll
        for (int n = 0; n < 4; ++n) {
            coln[n] = col0 + n * 16 + fr;
            bv[n] = bp[coln[n]];
        }
        if (sh) {
            float sigw = 1.f / (1.f + expf(-swp[0]));
#pragma unroll
            for (int m = 0; m < 4; ++m) {
#pragma unroll
                for (int i = 0; i < 4; ++i) {
                    int grow = mrow0 + m * 16 + fg * 4 + i;
                    if (grow < M) {
                        unsigned short* rowp = outS + (long long)grow * DDIM;
#pragma unroll
                        for (int n = 0; n < 4; ++n)
                            rowp[coln[n]] = f2bf((acc[m][n][i] + bv[n]) * sigw);
                    }
                }
            }
        } else {
#pragma unroll
            for (int m = 0; m < 4; ++m) {
#pragma unroll
                for (int i = 0; i < 4; ++i) {
                    int grow = mrow0 + m * 16 + fg * 4 + i;
                    if (grow < M) {
                        int p = oE + grow;
                        float wv = roww[p];
                        unsigned short* rowp = outM + (long long)p * DDIM;   // compact
#pragma unroll
                        for (int n = 0; n < 4; ++n)
                            rowp[coln[n]] = f2bf((acc[m][n][i] + bv[n]) * wv);
                    }
                }
            }
        }
    }
}

// ------- final: y = ycomp[pos0]+ycomp[pos1]+ysh ; LayerNorm over D -------
__global__ void k_ln(const unsigned short* __restrict__ yc,
                     const unsigned short* __restrict__ ysh,
                     const int* __restrict__ pos,
                     const float* __restrict__ g, const float* __restrict__ b,
                     float* __restrict__ out) {
    const int wid = threadIdx.x >> 6, lane = threadIdx.x & 63;
    const long long t = (long long)blockIdx.x * 4 + wid;
    const long long b0 = (long long)pos[2 * t] * DDIM;
    const long long b1 = (long long)pos[2 * t + 1] * DDIM;
    const long long bs = t * DDIM;
    float v[16];
    float s = 0.f, sq = 0.f;
#pragma unroll
    for (int j = 0; j < 2; ++j) {
        int c0 = (lane + 64 * j) * 8;
        uint4 a0 = *(const uint4*)(yc + b0 + c0);
        uint4 a1 = *(const uint4*)(yc + b1 + c0);
        uint4 a2 = *(const uint4*)(ysh + bs + c0);
        const unsigned* u0 = (const unsigned*)&a0;
        const unsigned* u1 = (const unsigned*)&a1;
        const unsigned* u2 = (const unsigned*)&a2;
#pragma unroll
        for (int qq = 0; qq < 4; ++qq) {
            float lo = bf2f((unsigned short)u0[qq]) + bf2f((unsigned short)u1[qq]) +
                       bf2f((unsigned short)u2[qq]);
            float hi = bf2f((unsigned short)(u0[qq] >> 16)) + bf2f((unsigned short)(u1[qq] >> 16)) +
                       bf2f((unsigned short)(u2[qq] >> 16));
            v[j * 8 + qq * 2] = lo;
            v[j * 8 + qq * 2 + 1] = hi;
            s += lo + hi;
            sq += lo * lo + hi * hi;
        }
    }
#pragma unroll
    for (int off = 32; off; off >>= 1) {
        s += __shfl_xor(s, off);
        sq += __shfl_xor(sq, off);
    }
    const float mean = s * (1.f / DDIM);
    const float var = sq * (1.f / DDIM) - mean * mean;
    const float inv = rsqrtf(var + 1e-5f);
#pragma unroll
    for (int j = 0; j < 2; ++j) {
        int c0 = (lane + 64 * j) * 8;
#pragma unroll
        for (int h = 0; h < 2; ++h) {
            float4 o4;
            float* op = (float*)&o4;
#pragma unroll
            for (int qq = 0; qq < 4; ++qq) {
                int k = h * 4 + qq;
                int col = c0 + k;
                op[qq] = (v[j * 8 + k] - mean) * inv * g[col] + b[col];
            }
            *(float4*)(out + bs + c0 + h * 4) = o4;
        }
    }
}

extern "C" void kernel_launch(void* const* d_in, const int* in_sizes, int n_in,
                              void* d_out, int out_size, void* d_ws, size_t ws_size,
                              hipStream_t stream) {
    const float* x    = (const float*)d_in[0];
    const float* rw   = (const float*)d_in[1];
    const float* rb   = (const float*)d_in[2];
    const float* w1   = (const float*)d_in[3];
    const float* b1   = (const float*)d_in[4];
    const float* gate = (const float*)d_in[5];
    const float* w2   = (const float*)d_in[6];
    const float* b2   = (const float*)d_in[7];
    const float* sw1  = (const float*)d_in[8];
    const float* sb1  = (const float*)d_in[9];
    const float* sgate= (const float*)d_in[10];
    const float* sw2  = (const float*)d_in[11];
    const float* sb2  = (const float*)d_in[12];
    const float* swt  = (const float*)d_in[13];
    const float* lng  = (const float*)d_in[14];
    const float* lnb  = (const float*)d_in[15];
    float* out = (float*)d_out;

    char* p = (char*)d_ws;
    auto take = [&](size_t n) { char* r = p; p += (n + 255) & ~(size_t)255; return r; };
    short* xb   = (short*)take((size_t)T_TOK * DDIM * 2);
    short* w1t  = (short*)take((size_t)NEXP * FDIM * DDIM * 2);
    short* w2t  = (short*)take((size_t)NEXP * DDIM * FDIM * 2);
    short* sw1t = (short*)take((size_t)F2DIM * DDIM * 2);
    short* sw2t = (short*)take((size_t)DDIM * F2DIM * 2);
    short* hbuf = (short*)take((size_t)2 * T_TOK * FDIM * 2);
    short* hs   = (short*)take((size_t)T_TOK * F2DIM * 2);
    unsigned short* ycomp = (unsigned short*)take((size_t)2 * T_TOK * DDIM * 2);
    unsigned short* ysh   = (unsigned short*)take((size_t)T_TOK * DDIM * 2);
    int* eid    = (int*)take((size_t)T_TOK * 2 * 4);
    float* ewt  = (float*)take((size_t)T_TOK * 2 * 4);
    int* rowtok = (int*)take((size_t)2 * T_TOK * 4);
    float* roww = (float*)take((size_t)2 * T_TOK * 4);
    int* pos    = (int*)take((size_t)2 * T_TOK * 4);
    int* bcnt   = (int*)take((size_t)NRBLK * 8 * 4);
    int* cnt    = (int*)take(64);
    int* offs   = (int*)take(64);

    // prep1: w1/sw1 tiled transpose (4352 blocks) + router (2048 blocks)
    k_prep1<<<NTPB1 + NRBLK, 256, 0, stream>>>(
        w1, sw1, (unsigned short*)w1t, (unsigned short*)sw1t,
        x, rw, rb, eid, ewt, bcnt, (unsigned short*)xb);

    // merged scan + scatter (deterministic, zero atomics)
    k_route<<<32, 256, 0, stream>>>(bcnt, eid, ewt, cnt, offs, rowtok, roww, pos);

    // fc1: FC1_T GEMM blocks + 4096 (w2) + 256 (sw2) fused transpose blocks
    k_fc<1><<<FC1_T + 4096 + 256, 256, 0, stream>>>(
        xb, xb, w1t, sw1t, b1, sb1, gate, sgate,
        (unsigned short*)hbuf, (unsigned short*)hs, cnt, offs, rowtok, roww, swt,
        w2, sw2, (unsigned short*)w2t, (unsigned short*)sw2t);
    // fc2: tiles = sum_e ceil(cnt/128)*8 (<= 1080) + shared 64*8=512
    k_fc<2><<<1592, 256, 0, stream>>>(
        hbuf, hs, w2t, sw2t, b2, sb2, (const float*)nullptr, (const float*)nullptr,
        ycomp, ysh, cnt, offs, rowtok, roww, swt,
        (const float*)nullptr, (const float*)nullptr,
        (unsigned short*)nullptr, (unsigned short*)nullptr);

    k_ln<<<T_TOK / 4, 256, 0, stream>>>(ycomp, ysh, pos, lng, lnb, out);
}

// Round 18
// 563.871 us; speedup vs baseline: 1.9619x; 1.0147x over previous
//
#include <hip/hip_runtime.h>
#include <hip/hip_bf16.h>
#include <stdint.h>

typedef __attribute__((ext_vector_type(8))) short bf16x8;
typedef __attribute__((ext_vector_type(4))) float f32x4;
typedef __attribute__((ext_vector_type(4))) unsigned short us4;

#define T_TOK 8192
#define DDIM 1024
#define FDIM 4096
#define F2DIM 2048
#define NEXP 8
#define NTPB1 4352     // prep1 transpose blocks: 4096(w1) + 256(sw1)
#define NRBLK 2048     // router blocks (4 tokens each)
#define FC1_T 5344     // fc1 GEMM block budget; ids >= FC1_T do w2/sw2 transpose

__device__ __forceinline__ unsigned short f2bf(float f) {
    unsigned u = __float_as_uint(f);
    u += 0x7fffu + ((u >> 16) & 1u);
    return (unsigned short)(u >> 16);
}
__device__ __forceinline__ float bf2f(unsigned short h) {
    return __uint_as_float(((unsigned)h) << 16);
}
__device__ __forceinline__ float gelu_fast(float v) {
    float u = 0.7978845608028654f * v * (1.0f + 0.044715f * v * v);
    float a = fabsf(u);
    float t = __expf(-2.0f * a);
    float th = (1.0f - t) / (1.0f + t);
    th = u < 0.0f ? -th : th;
    return 0.5f * v * (1.0f + th);
}

// async global->LDS, 16B per lane. LDS dest is wave-uniform base + lane*16.
__device__ __forceinline__ void gl2lds16(const void* g, void* l) {
    __builtin_amdgcn_global_load_lds(
        (const __attribute__((address_space(1))) unsigned int*)(unsigned long long)g,
        (__attribute__((address_space(3))) unsigned int*)(unsigned int)(unsigned long long)l,
        16, 0, 0);
}

// ---- one 128n x 64k transpose region -> 2 tiled 8KB units (R12-proven) ------
__device__ __forceinline__ void tp_block(const float* __restrict__ in,
                                         unsigned short* __restrict__ out,
                                         int Cin, long long ibase, int n0, int k0,
                                         long long unit0, float (*ts)[128], int tid) {
#pragma unroll
    for (int i = 0; i < 8; ++i) {
        int idx = tid + i * 256;
        int k = idx >> 5, t4 = idx & 31;
        float4 v = *(const float4*)(in + ibase + (long long)(k0 + k) * Cin + n0 + t4 * 4);
        *(float4*)&ts[k][t4 * 4] = v;
    }
    __syncthreads();
#pragma unroll
    for (int i = 0; i < 4; ++i) {
        int idx = tid + i * 256;           // 0..1023
        int u = idx >> 9, cid = idx & 511;
        int row = cid >> 2, c = cid & 3;
        int gc = c ^ ((row >> 1) & 3);
        const int kb = u * 32 + gc * 8;
        us4 o0, o1;
        o0.x = f2bf(ts[kb + 0][row]); o0.y = f2bf(ts[kb + 1][row]);
        o0.z = f2bf(ts[kb + 2][row]); o0.w = f2bf(ts[kb + 3][row]);
        o1.x = f2bf(ts[kb + 4][row]); o1.y = f2bf(ts[kb + 5][row]);
        o1.z = f2bf(ts[kb + 6][row]); o1.w = f2bf(ts[kb + 7][row]);
        unsigned short* dst = out + (unit0 + u) * 4096 + (long long)cid * 8;
        *(us4*)dst = o0;
        *(us4*)(dst + 4) = o1;
    }
}

// ===== prep1: w1/sw1 transpose (blocks < NTPB1) ∥ router (rest) ==============
__global__ void k_prep1(const float* __restrict__ w1, const float* __restrict__ sw1,
                        unsigned short* __restrict__ w1t, unsigned short* __restrict__ sw1t,
                        const float* __restrict__ x, const float* __restrict__ rw,
                        const float* __restrict__ rbv, int* __restrict__ eid,
                        float* __restrict__ ewt, int* __restrict__ bcnt,
                        unsigned short* __restrict__ xb) {
    const int blk = blockIdx.x;
    const int tid = threadIdx.x;

    if (blk < NTPB1) {
        __shared__ float ts[64][128];
        if (blk < 4096) {              // w1: 8 x [K=1024][N=4096]; NB=32, slabs=16
            int e = blk >> 9, l = blk & 511;
            int nb = l >> 4, ks = l & 15;
            tp_block(w1, w1t, 4096, (long long)e * 1024 * 4096,
                     nb * 128, ks * 64, (long long)e * 1024 + nb * 32 + ks * 2, ts, tid);
        } else {                       // sw1: [K=1024][N=2048]; NB=16, slabs=16
            int l = blk - 4096;
            int nb = l >> 4, ks = l & 15;
            tp_block(sw1, sw1t, 2048, 0, nb * 128, ks * 64, nb * 32 + ks * 2, ts, tid);
        }
        return;
    }

    // ---------------- router part (zero global atomics) ----------------
    __shared__ int hcnt[8];
    const int rblk = blk - NTPB1;
    const int wid = tid >> 6, lane = tid & 63;
    const int t = rblk * 4 + wid;
    if (tid < 8) hcnt[tid] = 0;
    __syncthreads();

    float acc[8];
#pragma unroll
    for (int e = 0; e < 8; ++e) acc[e] = 0.f;
    const float4* xr = (const float4*)(x + (long long)t * DDIM);
#pragma unroll
    for (int c = 0; c < 4; ++c) {
        float4 xv = xr[lane + 64 * c];
        int d0 = (lane + 64 * c) * 4;
        us4 o;
        o.x = f2bf(xv.x); o.y = f2bf(xv.y); o.z = f2bf(xv.z); o.w = f2bf(xv.w);
        *(us4*)(xb + (long long)t * DDIM + d0) = o;
        float xs[4] = {xv.x, xv.y, xv.z, xv.w};
#pragma unroll
        for (int j = 0; j < 4; ++j) {
            const float* wrow = rw + (long long)(d0 + j) * 8;
#pragma unroll
            for (int e = 0; e < 8; ++e) acc[e] += xs[j] * wrow[e];
        }
    }
#pragma unroll
    for (int off = 32; off; off >>= 1)
#pragma unroll
        for (int e = 0; e < 8; ++e) acc[e] += __shfl_xor(acc[e], off);
    if (lane == 0) {
        float lg[8];
#pragma unroll
        for (int e = 0; e < 8; ++e) lg[e] = acc[e] + rbv[e];
        int e0 = 0;
#pragma unroll
        for (int e = 1; e < 8; ++e) if (lg[e] > lg[e0]) e0 = e;
        int e1 = -1;
#pragma unroll
        for (int e = 0; e < 8; ++e) {
            if (e == e0) continue;
            if (e1 < 0 || lg[e] > lg[e1]) e1 = e;
        }
        float w0 = 1.f / (1.f + expf(lg[e1] - lg[e0]));
        eid[2 * t] = e0; eid[2 * t + 1] = e1;
        ewt[2 * t] = w0; ewt[2 * t + 1] = 1.f - w0;
        atomicAdd(&hcnt[e0], 1);   // LDS atomic (fast)
        atomicAdd(&hcnt[e1], 1);
    }
    __syncthreads();
    if (tid < 8) bcnt[rblk * 8 + tid] = hcnt[tid];
}

// ===== route: merged scan + scatter, 32 blocks, zero atomics =================
__global__ void k_route(const int* __restrict__ bcnt, const int* __restrict__ eid,
                        const float* __restrict__ ewt, int* __restrict__ cnt,
                        int* __restrict__ offs, int* __restrict__ rowtok,
                        float* __restrict__ roww, int* __restrict__ pos) {
    __shared__ int part[8][33];
    __shared__ int ctot[8];
    __shared__ int gbase[8];
    __shared__ int lb[64][8];
    const int tid = threadIdx.x;
    const int e = tid >> 5, j = tid & 31;
    int s = 0;
    for (int r = j * 64; r < j * 64 + 64; ++r) s += bcnt[r * 8 + e];
    part[e][j] = s;
    __syncthreads();
    if (j == 0) {                      // exclusive prefix over 32 partials
        int run = 0;
        for (int k = 0; k < 32; ++k) { int v = part[e][k]; part[e][k] = run; run += v; }
        ctot[e] = run;
    }
    __syncthreads();
    if (tid == 0) {
        int run = 0;
        for (int ee = 0; ee < NEXP; ++ee) { gbase[ee] = run; run += ctot[ee]; }
        if (blockIdx.x == 0) {
            int r2 = 0;
            for (int ee = 0; ee < NEXP; ++ee) { offs[ee] = r2; cnt[ee] = ctot[ee]; r2 += ctot[ee]; }
            offs[NEXP] = r2;
        }
    }
    __syncthreads();
    if (tid < 8) {                     // bases for this block's 64 router rows
        int ee = tid;
        int run = gbase[ee] + part[ee][blockIdx.x];
        int r0 = blockIdx.x * 64;
        for (int r = 0; r < 64; ++r) {
            lb[r][ee] = run;
            run += bcnt[(r0 + r) * 8 + ee];
        }
    }
    __syncthreads();
    // scatter this block's 256 tokens
    const int t = blockIdx.x * 256 + tid;
    const int rloc = tid >> 2;
    const int g = t & 3;
    const int lane = tid & 63, lbn = lane & ~3;
    int e0 = eid[2 * t], e1 = eid[2 * t + 1];
    int r0 = 0, r1 = 0;
#pragma unroll
    for (int q = 0; q < 4; ++q) {
        int oe0 = __shfl(e0, lbn + q, 64);
        int oe1 = __shfl(e1, lbn + q, 64);
        if (q < g) {
            r0 += (oe0 == e0) + (oe1 == e0);
            r1 += (oe0 == e1) + (oe1 == e1);
        }
    }
    int p0 = lb[rloc][e0] + r0;
    int p1 = lb[rloc][e1] + r1;
    rowtok[p0] = (t << 1);     roww[p0] = ewt[2 * t];     pos[2 * t] = p0;
    rowtok[p1] = (t << 1) | 1; roww[p1] = ewt[2 * t + 1]; pos[2 * t + 1] = p1;
}

// ---- grouped GEMM (R17 core) + (FC==1) fused w2/sw2 transpose ---------------
// LDS exactly 32KB, __launch_bounds__(256,4) (natural 64 VGPRs, no spill).
// Epilogue: per-wave full-tile fast path skips 64 bounds checks/thread.
template <int FC>
__launch_bounds__(256, 4)
__global__ void k_fc(const short* __restrict__ Amoe, const short* __restrict__ Ash,
                     const short* __restrict__ Bmoe, const short* __restrict__ Bsh,
                     const float* __restrict__ biasM, const float* __restrict__ biasS,
                     const float* __restrict__ gateM, const float* __restrict__ gateS,
                     unsigned short* __restrict__ outM, unsigned short* __restrict__ outS,
                     const int* __restrict__ cnt, const int* __restrict__ offs,
                     const int* __restrict__ rowtok, const float* __restrict__ roww,
                     const float* __restrict__ swp,
                     const float* __restrict__ w2raw, const float* __restrict__ sw2raw,
                     unsigned short* __restrict__ w2t_o, unsigned short* __restrict__ sw2t_o) {
    __shared__ __align__(16) char smem_raw[32768];

    if (FC == 1 && blockIdx.x >= FC1_T) {
        float (*ts)[128] = (float(*)[128])smem_raw;
        int tb = blockIdx.x - FC1_T;
        if (tb < 4096) {               // w2: 8 x [K=4096][N=1024]; NB=8, slabs=64
            int e = tb >> 9, l = tb & 511;
            int nb = l >> 6, ks = l & 63;
            tp_block(w2raw, w2t_o, 1024, (long long)e * 4096 * 1024,
                     nb * 128, ks * 64, (long long)e * 1024 + nb * 128 + ks * 2,
                     ts, threadIdx.x);
        } else {                       // sw2: [K=2048][N=1024]; NB=8, slabs=32
            int l = tb - 4096;
            int nb = l >> 5, ks = l & 31;
            tp_block(sw2raw, sw2t_o, 1024, 0, nb * 128, ks * 64,
                     nb * 64 + ks * 2, ts, threadIdx.x);
        }
        return;
    }

    // ---- tile decode ----
    int RBz[9];
    int T = 0;
#pragma unroll
    for (int zz = 0; zz < 9; ++zz) {
        int Mz = (zz < 8) ? cnt[zz] : T_TOK;
        int rbn = (Mz + 127) >> 7;
        int cbn = (FC == 1) ? ((zz < 8) ? 32 : 16) : 8;
        RBz[zz] = rbn;
        T += rbn * cbn;
    }
    const int ell = blockIdx.x;
    if (ell >= T) return;
    const int q = T >> 3, r = T & 7;
    const int xk = ell & 7, jj = ell >> 3;
    int t = (xk < r ? xk * (q + 1) : r * (q + 1) + (xk - r) * q) + jj;

    int z = 0, local = t;
    for (; z < 9; ++z) {
        int cbn = (FC == 1) ? ((z < 8) ? 32 : 16) : 8;
        int tz = RBz[z] * cbn;
        if (local < tz) break;
        local -= tz;
    }
    const int RB = RBz[z];
    int cb, rb;
    if (FC == 1) {                 // panel groups of 4: (cbg, rb, cbi)
        int grp = RB * 4;
        int cbg = local / grp;
        int r2 = local - cbg * grp;
        rb = r2 >> 2;
        cb = cbg * 4 + (r2 & 3);
    } else {                       // cb fastest: A-tile reuse (CBN = 8)
        rb = local >> 3;
        cb = local & 7;
    }

    const bool sh = (z == 8);
    const int Kd = (FC == 1) ? 1024 : (sh ? 2048 : 4096);
    const int Ncols = (FC == 1) ? (sh ? 2048 : 4096) : 1024;
    const int KB = Kd / 32;        // units per B column-panel
    const int M = sh ? T_TOK : cnt[z];
    const int oE = sh ? 0 : offs[z];

    const short* A = sh ? Ash : Amoe;
    const short* B = sh ? Bsh : Bmoe + (long long)z * 4194304;

    short* Asb = (short*)smem_raw;        // [2][4096]
    short* Bsb = Asb + 8192;              // [2][4096]

    const int tid = threadIdx.x, w = tid >> 6, lane = tid & 63;
    const int fr = lane & 15, fg = lane >> 4;
    const int wr = w >> 1, wc = w & 1;

    const short *ag0, *ag1;
    {
        int id = tid, row = id >> 2;
        int gc = (id & 3) ^ ((row >> 1) & 3);
        int rA = rb * 128 + row; if (rA > M - 1) rA = M - 1;
        long long rowix;
        if (FC == 1) rowix = sh ? (long long)rA : (long long)(rowtok[oE + rA] >> 1);
        else         rowix = sh ? (long long)rA : (long long)(oE + rA);
        ag0 = A + rowix * (long long)Kd + gc * 8;
    }
    {
        int id = tid + 256, row = id >> 2;
        int gc = (id & 3) ^ ((row >> 1) & 3);
        int rA = rb * 128 + row; if (rA > M - 1) rA = M - 1;
        long long rowix;
        if (FC == 1) rowix = sh ? (long long)rA : (long long)(rowtok[oE + rA] >> 1);
        else         rowix = sh ? (long long)rA : (long long)(oE + rA);
        ag1 = A + rowix * (long long)Kd + gc * 8;
    }
    const short* bb = B + (long long)cb * KB * 4096 + (long long)tid * 8;

    short* const a0d0 = Asb + w * 512;
    short* const a0d1 = Asb + 2048 + w * 512;
    short* const a1d0 = Asb + 4096 + w * 512;
    short* const a1d1 = Asb + 4096 + 2048 + w * 512;
    short* const b0d0 = Bsb + w * 512;
    short* const b0d1 = Bsb + 2048 + w * 512;
    short* const b1d0 = Bsb + 4096 + w * 512;
    short* const b1d1 = Bsb + 4096 + 2048 + w * 512;

    f32x4 acc[4][4];
#pragma unroll
    for (int m = 0; m < 4; ++m)
#pragma unroll
        for (int n = 0; n < 4; ++n)
            acc[m][n] = (f32x4){0.f, 0.f, 0.f, 0.f};

    const int slot = fg ^ ((fr >> 1) & 3);     // measured 0-conflict formula
    const int arow0 = wr * 64 + fr;
    const int brow0 = wc * 64 + fr;
    const int nk = Kd / 64;

    for (int kt = 0; kt < nk; ++kt) {
        gl2lds16(ag0, a0d0);       gl2lds16(ag0 + 32, a1d0);
        gl2lds16(ag1, a0d1);       gl2lds16(ag1 + 32, a1d1);
        gl2lds16(bb, b0d0);        gl2lds16(bb + 2048, b0d1);
        gl2lds16(bb + 4096, b1d0); gl2lds16(bb + 6144, b1d1);
        ag0 += 64; ag1 += 64; bb += 8192;
        __syncthreads();

#pragma unroll
        for (int s = 0; s < 2; ++s) {
            bf16x8 a[4], b[4];
#pragma unroll
            for (int m = 0; m < 4; ++m)
                a[m] = *(const bf16x8*)(Asb + s * 4096 + (arow0 + m * 16) * 32 + slot * 8);
#pragma unroll
            for (int n = 0; n < 4; ++n)
                b[n] = *(const bf16x8*)(Bsb + s * 4096 + (brow0 + n * 16) * 32 + slot * 8);
#pragma unroll
            for (int m = 0; m < 4; ++m)
#pragma unroll
                for (int n = 0; n < 4; ++n)
                    acc[m][n] = __builtin_amdgcn_mfma_f32_16x16x32_bf16(a[m], b[n], acc[m][n], 0, 0, 0);
        }
        __syncthreads();
    }

    // ---- epilogue. C/D layout: col=lane&15, row=(lane>>4)*4+i. ----
    const int mrow0 = rb * 128 + wr * 64;
    const int col0 = cb * 128 + wc * 64;
    const bool full = (M - mrow0 >= 64);   // wave's 64 rows all valid

    if (FC == 1) {
        const float* bp = sh ? biasS : biasM + (long long)z * FDIM;
        const float* gp = sh ? gateS : gateM + (long long)z * FDIM;
        unsigned short* outp = sh ? outS : outM;
        const long long obase = sh ? 0 : (long long)oE;
        float bv[4], gv[4]; int coln[4];
#pragma unroll
        for (int n = 0; n < 4; ++n) {
            coln[n] = col0 + n * 16 + fr;
            bv[n] = bp[coln[n]];
            gv[n] = gp[coln[n]];
        }
        if (full) {
#pragma unroll
            for (int m = 0; m < 4; ++m) {
#pragma unroll
                for (int i = 0; i < 4; ++i) {
                    int grow = mrow0 + m * 16 + fg * 4 + i;
                    unsigned short* rowp = outp + (obase + grow) * (long long)Ncols;
#pragma unroll
                    for (int n = 0; n < 4; ++n) {
                        float v = (acc[m][n][i] + bv[n]) * gv[n];
                        rowp[coln[n]] = f2bf(gelu_fast(v));
                    }
                }
            }
        } else {
#pragma unroll
            for (int m = 0; m < 4; ++m) {
#pragma unroll
                for (int i = 0; i < 4; ++i) {
                    int grow = mrow0 + m * 16 + fg * 4 + i;
                    if (grow < M) {
                        unsigned short* rowp = outp + (obase + grow) * (long long)Ncols;
#pragma unroll
                        for (int n = 0; n < 4; ++n) {
                            float v = (acc[m][n][i] + bv[n]) * gv[n];
                            rowp[coln[n]] = f2bf(gelu_fast(v));
                        }
                    }
                }
            }
        }
    } else {
        float bv[4]; int coln[4];
        const float* bp = sh ? biasS : biasM + (long long)z * DDIM;
#pragma unroll
        for (int n = 0; n < 4; ++n) {
            coln[n] = col0 + n * 16 + fr;
            bv[n] = bp[coln[n]];
        }
        if (sh) {
            float sigw = 1.f / (1.f + expf(-swp[0]));
#pragma unroll
            for (int m = 0; m < 4; ++m) {
#pragma unroll
                for (int i = 0; i < 4; ++i) {
                    int grow = mrow0 + m * 16 + fg * 4 + i;
                    unsigned short* rowp = outS + (long long)grow * DDIM;   // M=8192: always full
#pragma unroll
                    for (int n = 0; n < 4; ++n)
                        rowp[coln[n]] = f2bf((acc[m][n][i] + bv[n]) * sigw);
                }
            }
        } else if (full) {
#pragma unroll
            for (int m = 0; m < 4; ++m) {
#pragma unroll
                for (int i = 0; i < 4; ++i) {
                    int grow = mrow0 + m * 16 + fg * 4 + i;
                    int p = oE + grow;
                    float wv = roww[p];
                    unsigned short* rowp = outM + (long long)p * DDIM;   // compact
#pragma unroll
                    for (int n = 0; n < 4; ++n)
                        rowp[coln[n]] = f2bf((acc[m][n][i] + bv[n]) * wv);
                }
            }
        } else {
#pragma unroll
            for (int m = 0; m < 4; ++m) {
#pragma unroll
                for (int i = 0; i < 4; ++i) {
                    int grow = mrow0 + m * 16 + fg * 4 + i;
                    if (grow < M) {
                        int p = oE + grow;
                        float wv = roww[p];
                        unsigned short* rowp = outM + (long long)p * DDIM;
#pragma unroll
                        for (int n = 0; n < 4; ++n)
                            rowp[coln[n]] = f2bf((acc[m][n][i] + bv[n]) * wv);
                    }
                }
            }
        }
    }
}

// ------- final: y = ycomp[pos0]+ycomp[pos1]+ysh ; LayerNorm over D -------
__global__ void k_ln(const unsigned short* __restrict__ yc,
                     const unsigned short* __restrict__ ysh,
                     const int* __restrict__ pos,
                     const float* __restrict__ g, const float* __restrict__ b,
                     float* __restrict__ out) {
    const int wid = threadIdx.x >> 6, lane = threadIdx.x & 63;
    const long long t = (long long)blockIdx.x * 4 + wid;
    const long long b0 = (long long)pos[2 * t] * DDIM;
    const long long b1 = (long long)pos[2 * t + 1] * DDIM;
    const long long bs = t * DDIM;
    float v[16];
    float s = 0.f, sq = 0.f;
#pragma unroll
    for (int j = 0; j < 2; ++j) {
        int c0 = (lane + 64 * j) * 8;
        uint4 a0 = *(const uint4*)(yc + b0 + c0);
        uint4 a1 = *(const uint4*)(yc + b1 + c0);
        uint4 a2 = *(const uint4*)(ysh + bs + c0);
        const unsigned* u0 = (const unsigned*)&a0;
        const unsigned* u1 = (const unsigned*)&a1;
        const unsigned* u2 = (const unsigned*)&a2;
#pragma unroll
        for (int qq = 0; qq < 4; ++qq) {
            float lo = bf2f((unsigned short)u0[qq]) + bf2f((unsigned short)u1[qq]) +
                       bf2f((unsigned short)u2[qq]);
            float hi = bf2f((unsigned short)(u0[qq] >> 16)) + bf2f((unsigned short)(u1[qq] >> 16)) +
                       bf2f((unsigned short)(u2[qq] >> 16));
            v[j * 8 + qq * 2] = lo;
            v[j * 8 + qq * 2 + 1] = hi;
            s += lo + hi;
            sq += lo * lo + hi * hi;
        }
    }
#pragma unroll
    for (int off = 32; off; off >>= 1) {
        s += __shfl_xor(s, off);
        sq += __shfl_xor(sq, off);
    }
    const float mean = s * (1.f / DDIM);
    const float var = sq * (1.f / DDIM) - mean * mean;
    const float inv = rsqrtf(var + 1e-5f);
#pragma unroll
    for (int j = 0; j < 2; ++j) {
        int c0 = (lane + 64 * j) * 8;
#pragma unroll
        for (int h = 0; h < 2; ++h) {
            float4 o4;
            float* op = (float*)&o4;
#pragma unroll
            for (int qq = 0; qq < 4; ++qq) {
                int k = h * 4 + qq;
                int col = c0 + k;
                op[qq] = (v[j * 8 + k] - mean) * inv * g[col] + b[col];
            }
            *(float4*)(out + bs + c0 + h * 4) = o4;
        }
    }
}

extern "C" void kernel_launch(void* const* d_in, const int* in_sizes, int n_in,
                              void* d_out, int out_size, void* d_ws, size_t ws_size,
                              hipStream_t stream) {
    const float* x    = (const float*)d_in[0];
    const float* rw   = (const float*)d_in[1];
    const float* rb   = (const float*)d_in[2];
    const float* w1   = (const float*)d_in[3];
    const float* b1   = (const float*)d_in[4];
    const float* gate = (const float*)d_in[5];
    const float* w2   = (const float*)d_in[6];
    const float* b2   = (const float*)d_in[7];
    const float* sw1  = (const float*)d_in[8];
    const float* sb1  = (const float*)d_in[9];
    const float* sgate= (const float*)d_in[10];
    const float* sw2  = (const float*)d_in[11];
    const float* sb2  = (const float*)d_in[12];
    const float* swt  = (const float*)d_in[13];
    const float* lng  = (const float*)d_in[14];
    const float* lnb  = (const float*)d_in[15];
    float* out = (float*)d_out;

    char* p = (char*)d_ws;
    auto take = [&](size_t n) { char* r = p; p += (n + 255) & ~(size_t)255; return r; };
    short* xb   = (short*)take((size_t)T_TOK * DDIM * 2);
    short* w1t  = (short*)take((size_t)NEXP * FDIM * DDIM * 2);
    short* w2t  = (short*)take((size_t)NEXP * DDIM * FDIM * 2);
    short* sw1t = (short*)take((size_t)F2DIM * DDIM * 2);
    short* sw2t = (short*)take((size_t)DDIM * F2DIM * 2);
    short* hbuf = (short*)take((size_t)2 * T_TOK * FDIM * 2);
    short* hs   = (short*)take((size_t)T_TOK * F2DIM * 2);
    unsigned short* ycomp = (unsigned short*)take((size_t)2 * T_TOK * DDIM * 2);
    unsigned short* ysh   = (unsigned short*)take((size_t)T_TOK * DDIM * 2);
    int* eid    = (int*)take((size_t)T_TOK * 2 * 4);
    float* ewt  = (float*)take((size_t)T_TOK * 2 * 4);
    int* rowtok = (int*)take((size_t)2 * T_TOK * 4);
    float* roww = (float*)take((size_t)2 * T_TOK * 4);
    int* pos    = (int*)take((size_t)2 * T_TOK * 4);
    int* bcnt   = (int*)take((size_t)NRBLK * 8 * 4);
    int* cnt    = (int*)take(64);
    int* offs   = (int*)take(64);

    // prep1: w1/sw1 tiled transpose (4352 blocks) + router (2048 blocks)
    k_prep1<<<NTPB1 + NRBLK, 256, 0, stream>>>(
        w1, sw1, (unsigned short*)w1t, (unsigned short*)sw1t,
        x, rw, rb, eid, ewt, bcnt, (unsigned short*)xb);

    // merged scan + scatter (deterministic, zero atomics)
    k_route<<<32, 256, 0, stream>>>(bcnt, eid, ewt, cnt, offs, rowtok, roww, pos);

    // fc1: FC1_T GEMM blocks + 4096 (w2) + 256 (sw2) fused transpose blocks
    k_fc<1><<<FC1_T + 4096 + 256, 256, 0, stream>>>(
        xb, xb, w1t, sw1t, b1, sb1, gate, sgate,
        (unsigned short*)hbuf, (unsigned short*)hs, cnt, offs, rowtok, roww, swt,
        w2, sw2, (unsigned short*)w2t, (unsigned short*)sw2t);
    // fc2: tiles = sum_e ceil(cnt/128)*8 (<= 1080) + shared 64*8=512
    k_fc<2><<<1592, 256, 0, stream>>>(
        hbuf, hs, w2t, sw2t, b2, sb2, (const float*)nullptr, (const float*)nullptr,
        ycomp, ysh, cnt, offs, rowtok, roww, swt,
        (const float*)nullptr, (const float*)nullptr,
        (unsigned short*)nullptr, (unsigned short*)nullptr);

    k_ln<<<T_TOK / 4, 256, 0, stream>>>(ycomp, ysh, pos, lng, lnb, out);
}